// Round 1
// baseline (111.067 us; speedup 1.0000x reference)
//
#include <hip/hip_runtime.h>

// RaySamples: per-ray (K=128) exclusive scan of delta*density, then
//   T = exp(-acc_excl), w = T[k] - T[k+1]  (== alpha*T algebraically).
// Layout trick: K=128 fp32 = 2 rays per wave64 at one float4 per lane;
// rays are contiguous, so flat float4 index == coalesced access AND the
// ray boundary lands exactly on the lane-32 boundary -> segmented scan
// via __shfl_up(width=32). Memory-bound: 134 MB total traffic.

__global__ __launch_bounds__(256) void RaySamples_34454227648765_kernel(
    const float* __restrict__ dens, const float* __restrict__ delt,
    float* __restrict__ outw, float* __restrict__ outT, int n4)
{
    int i = blockIdx.x * blockDim.x + threadIdx.x;  // float4 index
    if (i >= n4) return;

    const float4 d  = reinterpret_cast<const float4*>(dens)[i];
    const float4 dl = reinterpret_cast<const float4*>(delt)[i];

    float dd0 = d.x * dl.x;
    float dd1 = d.y * dl.y;
    float dd2 = d.z * dl.z;
    float dd3 = d.w * dl.w;

    float s = dd0 + dd1 + dd2 + dd3;   // this lane's total optical depth

    // Inclusive scan of per-lane totals across the 32-lane ray segment.
    int lane = threadIdx.x & 31;
    float inc = s;
    #pragma unroll
    for (int off = 1; off < 32; off <<= 1) {
        float v = __shfl_up(inc, off, 32);
        inc += (lane >= off) ? v : 0.0f;
    }
    float a0 = inc - s;        // exclusive optical depth before element 0
    float a1 = a0 + dd0;
    float a2 = a1 + dd1;
    float a3 = a2 + dd2;
    float a4 = a3 + dd3;

    float t0 = __expf(-a0);
    float t1 = __expf(-a1);
    float t2 = __expf(-a2);
    float t3 = __expf(-a3);
    float t4 = __expf(-a4);

    float4 T = make_float4(t0, t1, t2, t3);
    // w[k] = (1 - exp(-dd[k])) * exp(-a[k]) = exp(-a[k]) - exp(-a[k+1])
    float4 W = make_float4(t0 - t1, t1 - t2, t2 - t3, t3 - t4);

    reinterpret_cast<float4*>(outw)[i] = W;
    reinterpret_cast<float4*>(outT)[i] = T;
}

extern "C" void kernel_launch(void* const* d_in, const int* in_sizes, int n_in,
                              void* d_out, int out_size, void* d_ws, size_t ws_size,
                              hipStream_t stream) {
    const float* dens = (const float*)d_in[0];   // densities [N,K,1] fp32
    const float* delt = (const float*)d_in[1];   // deltas    [N,K,1] fp32
    float* out = (float*)d_out;                  // [weights | transmittance]

    const int NK = in_sizes[0];                  // N*K = 8388608
    const int n4 = NK / 4;                       // float4 quads
    float* outw = out;
    float* outT = out + NK;

    const int block = 256;
    const int grid = (n4 + block - 1) / block;   // 8192 blocks
    RaySamples_34454227648765_kernel<<<grid, block, 0, stream>>>(
        dens, delt, outw, outT, n4);
}